// Round 8
// baseline (361.952 us; speedup 1.0000x reference)
//
#include <hip/hip_runtime.h>
#include <hip/hip_bf16.h>

#define NB 2
#define NL 2048
#define ND 2048
#define NH 16
#define NDK 128
// SCALE * log2(e): softmax tracked in exp2 domain; folded into Q at RoPE-convert time
#define SCALE2 0.12753102866606474f

#define AS1 __attribute__((address_space(1)))
#define AS3 __attribute__((address_space(3)))

typedef __attribute__((ext_vector_type(8))) __bf16 bf16x8;
typedef __attribute__((ext_vector_type(4))) float f32x4;

__device__ __forceinline__ unsigned short f2bf(float f) {
    union { float f; unsigned u; } v; v.f = f;
    return (unsigned short)((v.u + 0x7fffu + ((v.u >> 16) & 1u)) >> 16);
}
__device__ __forceinline__ float bf2f(unsigned short h) {
    union { unsigned u; float f; } v; v.u = ((unsigned)h) << 16;
    return v.f;
}

// ============ merged prep: x->bf16 convert + w_qkv transpose + w_o transpose ============
__device__ __forceinline__ void transpose_tile(const float* __restrict__ in,
                                               unsigned short* __restrict__ outp,
                                               int R, int C, int bx, int by, int tid)
{
    __shared__ float T[64][65];
    const int tr0 = by * 64;
    const int tc0 = bx * 64;
    const int r = tid >> 2;
    const int q = tid & 3;
    const float* src = in + (size_t)(tr0 + r) * C + tc0 + q * 16;
    #pragma unroll
    for (int i = 0; i < 4; i++) {
        float4 f = *(const float4*)(src + 4 * i);
        T[r][q * 16 + 4 * i + 0] = f.x;
        T[r][q * 16 + 4 * i + 1] = f.y;
        T[r][q * 16 + 4 * i + 2] = f.z;
        T[r][q * 16 + 4 * i + 3] = f.w;
    }
    __syncthreads();
    unsigned short tmp[16];
    #pragma unroll
    for (int i = 0; i < 16; i++) tmp[i] = f2bf(T[q * 16 + i][r]);
    unsigned short* dst = outp + (size_t)(tc0 + r) * R + tr0 + q * 16;
    *(uint4*)dst       = *(uint4*)&tmp[0];
    *(uint4*)(dst + 8) = *(uint4*)&tmp[8];
}

__global__ __launch_bounds__(256)
void prep_kernel(const float* __restrict__ x, unsigned short* __restrict__ x_bf,
                 const float* __restrict__ w_qkv, unsigned short* __restrict__ Wt,
                 const float* __restrict__ w_o, unsigned short* __restrict__ Wt_o)
{
    const int bid = blockIdx.x;
    const int tid = threadIdx.x;
    if (bid < 4096) {
        int i = bid * 256 + tid;
        const float4 a = ((const float4*)x)[2 * i];
        const float4 b = ((const float4*)x)[2 * i + 1];
        unsigned short t[8] = { f2bf(a.x), f2bf(a.y), f2bf(a.z), f2bf(a.w),
                                f2bf(b.x), f2bf(b.y), f2bf(b.z), f2bf(b.w) };
        ((uint4*)x_bf)[i] = *(uint4*)t;
    } else if (bid < 7168) {
        int b2 = bid - 4096;                      // (96, 32)
        transpose_tile(w_qkv, Wt, ND, 3 * ND, b2 % 96, b2 / 96, tid);
    } else {
        int b3 = bid - 7168;                      // (32, 32)
        transpose_tile(w_o, Wt_o, ND, ND, b3 & 31, b3 >> 5, tid);
    }
}

// ============ pipelined bf16 GEMM (validated): C = A @ Bt^T =============================
// Two barriers per K-step, 3-buffer, vmcnt(8/4/0). DO NOT touch the K-loop schedule:
// rounds 1/2 (4-phase) and 6 (single-barrier) both regressed it (m131-m140 class null).
template<int EPI>
__global__ __launch_bounds__(256)
void gemm_bf16(const unsigned short* __restrict__ A, const unsigned short* __restrict__ Bt,
               float* __restrict__ y_dst,
               unsigned short* __restrict__ q_raw,
               float* __restrict__ k_dst, float* __restrict__ v_dst,
               int K, int NT)
{
    __shared__ __align__(16) unsigned short As[3][128][32];
    __shared__ __align__(16) unsigned short Bs[3][128][32];

    const int tid = threadIdx.x;
    const int lane = tid & 63;
    const int l16 = lane & 15, g = lane >> 4;
    const int w = tid >> 6;
    const int wr = w >> 1, wc = w & 1;

    const int cpn = NT >> 3;
    const int bid = blockIdx.x;
    const int xcd = bid & 7, local = bid >> 3;
    const int bx = xcd * cpn + local % cpn;
    const int by = local / cpn;
    const int m0 = by * 128, n0 = bx * 128;

    const int rowl = (w << 4) + (lane >> 2);
    const int swl = (rowl >> 1) & 3;
    const int kofl = ((lane & 3) ^ swl) << 3;
    const unsigned short* gA = A + (size_t)(m0 + rowl) * K + kofl;
    const unsigned short* gB = Bt + (size_t)(n0 + rowl) * K + kofl;
    const int ldsoff = (w << 10) + (lane << 4);

    f32x4 acc[4][4] = {};
    const int NTILES = K >> 5;

    auto STAGE = [&](int t, int buf) {
        const int k0 = t << 5;
        char* baseA = (char*)&As[buf][0][0] + ldsoff;
        char* baseB = (char*)&Bs[buf][0][0] + ldsoff;
        #pragma unroll
        for (int i = 0; i < 2; i++) {
            __builtin_amdgcn_global_load_lds((const AS1 void*)(gA + (size_t)i * 64 * K + k0),
                                             (AS3 void*)(baseA + i * 4096), 16, 0, 0);
            __builtin_amdgcn_global_load_lds((const AS1 void*)(gB + (size_t)i * 64 * K + k0),
                                             (AS3 void*)(baseB + i * 4096), 16, 0, 0);
        }
    };

    const int rsw = (l16 >> 1) & 3;

    STAGE(0, 0); STAGE(1, 1);

    int bufC = 0;
    for (int t = 0; t < NTILES; t++) {
        const int bufS = (bufC == 0) ? 2 : bufC - 1;
        if (t + 2 < NTILES) STAGE(t + 2, bufS);
        if (t + 2 < NTILES)      asm volatile("s_waitcnt vmcnt(8)" ::: "memory");
        else if (t + 1 < NTILES) asm volatile("s_waitcnt vmcnt(4)" ::: "memory");
        else                     asm volatile("s_waitcnt vmcnt(0)" ::: "memory");
        __builtin_amdgcn_s_barrier();
        __builtin_amdgcn_sched_barrier(0);

        const char* pa = (const char*)&As[bufC][0][0];
        const char* pb = (const char*)&Bs[bufC][0][0];
        bf16x8 af[4], bfr[4];
        #pragma unroll
        for (int r = 0; r < 4; r++) {
            int row = wr * 64 + r * 16 + l16;
            af[r] = *(const bf16x8*)(pa + row * 64 + ((g ^ rsw) << 4));
        }
        #pragma unroll
        for (int c = 0; c < 4; c++) {
            int row = wc * 64 + c * 16 + l16;
            bfr[c] = *(const bf16x8*)(pb + row * 64 + ((g ^ rsw) << 4));
        }
        #pragma unroll
        for (int r = 0; r < 4; r++)
            #pragma unroll
            for (int c = 0; c < 4; c++)
                acc[r][c] = __builtin_amdgcn_mfma_f32_16x16x32_bf16(af[r], bfr[c], acc[r][c], 0, 0, 0);

        __builtin_amdgcn_s_barrier();
        __builtin_amdgcn_sched_barrier(0);
        bufC = (bufC == 2) ? 0 : bufC + 1;
    }

    if constexpr (EPI == 0) {
        const int m3 = bx >> 4, h = bx & 15;
        #pragma unroll
        for (int r = 0; r < 4; r++) {
            int mrow = m0 + wr * 64 + r * 16 + g * 4;
            int b = mrow >> 11, l = mrow & 2047;
            size_t rb = ((size_t)(b * NH + h) * NL + l) * NDK;
            #pragma unroll
            for (int c = 0; c < 4; c++) {
                int dk = wc * 64 + c * 16 + l16;
                #pragma unroll
                for (int i = 0; i < 4; i++) {
                    float val = acc[r][c][i];
                    size_t off = rb + (size_t)i * NDK + dk;
                    if (m3 == 0) q_raw[off] = f2bf(val);
                    else if (m3 == 1) k_dst[off] = val;
                    else v_dst[off] = val;
                }
            }
        }
    } else {
        #pragma unroll
        for (int r = 0; r < 4; r++) {
            int mrow = m0 + wr * 64 + r * 16 + g * 4;
            #pragma unroll
            for (int c = 0; c < 4; c++) {
                int ncol = n0 + wc * 64 + c * 16 + l16;
                #pragma unroll
                for (int i = 0; i < 4; i++)
                    y_dst[(size_t)(mrow + i) * ND + ncol] = acc[r][c][i];
            }
        }
    }
}

// ============ merged mid: RoPE-k (float4) + per-head V transpose ========================
__global__ __launch_bounds__(256)
void mid_kernel(float* __restrict__ kp, unsigned short* __restrict__ k_bf,
                const float* __restrict__ ct, const float* __restrict__ st,
                const float* __restrict__ v, unsigned short* __restrict__ vt)
{
    const int bid = blockIdx.x;
    const int tid = threadIdx.x;
    if (bid < 4096) {
        int idx = bid * 256 + tid;
        int d = (idx & 15) << 2;
        int rr = idx >> 4;
        size_t ro = (size_t)rr * NDK;
        int l = rr & (NL - 1);
        float4 c  = *(const float4*)(ct + l * 64 + d);
        float4 s  = *(const float4*)(st + l * 64 + d);
        float4 t1 = *(const float4*)(kp + ro + d);
        float4 t2 = *(const float4*)(kp + ro + d + 64);
        float4 o1, o2;
        o1.x = t1.x * c.x - t2.x * s.x;  o2.x = t1.x * s.x + t2.x * c.x;
        o1.y = t1.y * c.y - t2.y * s.y;  o2.y = t1.y * s.y + t2.y * c.y;
        o1.z = t1.z * c.z - t2.z * s.z;  o2.z = t1.z * s.z + t2.z * c.z;
        o1.w = t1.w * c.w - t2.w * s.w;  o2.w = t1.w * s.w + t2.w * c.w;
        *(float4*)(kp + ro + d)      = o1;
        *(float4*)(kp + ro + d + 64) = o2;
        unsigned short u1[4] = { f2bf(o1.x), f2bf(o1.y), f2bf(o1.z), f2bf(o1.w) };
        unsigned short u2[4] = { f2bf(o2.x), f2bf(o2.y), f2bf(o2.z), f2bf(o2.w) };
        *(uint2*)(k_bf + ro + d)      = *(uint2*)u1;
        *(uint2*)(k_bf + ro + d + 64) = *(uint2*)u2;
    } else {
        __shared__ float T[64][65];
        int b2 = bid - 4096;                  // (2, 32, 32)
        const int bh = b2 >> 6;
        const int l0 = ((b2 >> 1) & 31) * 64;
        const int d0 = (b2 & 1) * 64;
        const int r = tid >> 2;
        const int q = tid & 3;
        const float* src = v + (size_t)bh * NL * NDK + (size_t)(l0 + r) * NDK + d0 + q * 16;
        #pragma unroll
        for (int i = 0; i < 4; i++) {
            float4 f = *(const float4*)(src + 4 * i);
            T[r][q * 16 + 4 * i + 0] = f.x;
            T[r][q * 16 + 4 * i + 1] = f.y;
            T[r][q * 16 + 4 * i + 2] = f.z;
            T[r][q * 16 + 4 * i + 3] = f.w;
        }
        __syncthreads();
        unsigned short tmp[16];
        #pragma unroll
        for (int i = 0; i < 16; i++) tmp[i] = f2bf(T[q * 16 + i][r]);
        unsigned short* dst = vt + (size_t)bh * NDK * NL + (size_t)(d0 + r) * NL + l0 + q * 16;
        *(uint4*)dst       = *(uint4*)&tmp[0];
        *(uint4*)(dst + 8) = *(uint4*)&tmp[8];
    }
}

// ============ MFMA flash attention (round-0 validated: paired two-half blocks) ==========
// grid (32 bh, 16 by); block does jq = 31-by then by -> perfect balance (33 units/block)
// + L2-warm K/V reuse. Round-8 local changes only:
//  (1) SCALE2 folded into Q's cos/sin at RoPE-convert (16 muls/half vs 16 muls/tile);
//  (2) causal mask applied ONLY on the peeled diagonal tile (kv0 == qb) -- all earlier
//      tiles are provably unmasked (col_max = kv0+63 < qb <= row_min). Wave-uniform
//      specialization; o-rescale stays unconditional (rule-20 safe).
__global__ __launch_bounds__(256)
void attn_kernel(const unsigned short* __restrict__ q,
                 const unsigned short* __restrict__ k,
                 const unsigned short* __restrict__ vt,
                 unsigned short* __restrict__ attn_out,
                 const float* __restrict__ ct, const float* __restrict__ st)
{
    __shared__ __align__(16) unsigned short Ks[64][128];
    __shared__ __align__(16) unsigned short Vts[128][64];
    __shared__ __align__(16) unsigned short Ps[4][16][64];

    char* const ksb = (char*)&Ks[0][0];
    char* const vsb = (char*)&Vts[0][0];
    char* const psb = (char*)&Ps[0][0][0];

    const int tid = threadIdx.x, lane = tid & 63, w = tid >> 6;
    const int l16 = lane & 15, g = lane >> 4;
    const int bh = blockIdx.x;
    const int b = bh >> 4, h = bh & 15;
    const size_t base = (size_t)bh * NL * NDK;

    const int krow = tid >> 2;
    const int kq = tid & 3;
    const int kwb = krow * 256 + kq * 64;
    const int kwx = (krow & 7) << 4;
    const int vrow = tid >> 1;
    const int vh = tid & 1;
    const int vwb = vrow * 128 + vh * 64;
    const int vwx = (vrow & 7) << 4;

    const int rdx = (l16 & 7) << 4;

    const unsigned short* const kbase = k + base + (size_t)krow * NDK + kq * 32;
    const unsigned short* const vbase = vt + base + (size_t)vrow * NL + vh * 32;

    for (int half = 0; half < 2; half++) {
        const int jq = half ? (int)blockIdx.y : 31 - (int)blockIdx.y;
        const int qb = jq * 64;

        // ---- Q load with fused RoPE (SCALE2 folded into cos/sin) ----
        bf16x8 aq[4];
        {
            const int l = qb + w * 16 + l16;
            const unsigned short* src = q + base + (size_t)l * NDK + g * 8;
            union { bf16x8 v; unsigned short s[8]; } raw[4], outv[4];
            #pragma unroll
            for (int ks2 = 0; ks2 < 4; ks2++) raw[ks2].v = *(const bf16x8*)(src + ks2 * 32);
            const float* cb = ct + (size_t)l * 64 + g * 8;
            const float* sb = st + (size_t)l * 64 + g * 8;
            float cv[2][8], sv2[2][8];
            #pragma unroll
            for (int hh = 0; hh < 2; hh++) {
                float4 c0 = *(const float4*)(cb + 32 * hh);
                float4 c1 = *(const float4*)(cb + 32 * hh + 4);
                float4 s0 = *(const float4*)(sb + 32 * hh);
                float4 s1 = *(const float4*)(sb + 32 * hh + 4);
                cv[hh][0]=c0.x*SCALE2; cv[hh][1]=c0.y*SCALE2; cv[hh][2]=c0.z*SCALE2; cv[hh][3]=c0.w*SCALE2;
                cv[hh][4]=c1.x*SCALE2; cv[hh][5]=c1.y*SCALE2; cv[hh][6]=c1.z*SCALE2; cv[hh][7]=c1.w*SCALE2;
                sv2[hh][0]=s0.x*SCALE2; sv2[hh][1]=s0.y*SCALE2; sv2[hh][2]=s0.z*SCALE2; sv2[hh][3]=s0.w*SCALE2;
                sv2[hh][4]=s1.x*SCALE2; sv2[hh][5]=s1.y*SCALE2; sv2[hh][6]=s1.z*SCALE2; sv2[hh][7]=s1.w*SCALE2;
            }
            #pragma unroll
            for (int hh = 0; hh < 2; hh++)
                #pragma unroll
                for (int j = 0; j < 8; j++) {
                    float t1 = bf2f(raw[hh].s[j]), t2 = bf2f(raw[hh + 2].s[j]);
                    float c = cv[hh][j], s = sv2[hh][j];
                    outv[hh].s[j]     = f2bf(t1 * c - t2 * s);
                    outv[hh + 2].s[j] = f2bf(t1 * s + t2 * c);
                }
            #pragma unroll
            for (int ks2 = 0; ks2 < 4; ks2++) aq[ks2] = outv[ks2].v;
        }

        f32x4 o[8] = {};
        float m_r[4], lv[4];
        #pragma unroll
        for (int i = 0; i < 4; i++) { m_r[i] = -1e30f; lv[i] = 0.f; }

        // ---- T14 prologue: tile 0 into named registers ----
        uint4 pk0, pk1, pk2, pk3, pv0, pv1, pv2, pv3;
        {
            const unsigned short* ks = kbase;           // kv0 = 0
            pk0 = *(const uint4*)(ks);
            pk1 = *(const uint4*)(ks + 8);
            pk2 = *(const uint4*)(ks + 16);
            pk3 = *(const uint4*)(ks + 24);
            const unsigned short* vs = vbase;
            pv0 = *(const uint4*)(vs);
            pv1 = *(const uint4*)(vs + 8);
            pv2 = *(const uint4*)(vs + 16);
            pv3 = *(const uint4*)(vs + 24);
        }

        auto TILE = [&](int kv0, bool diag) {
            __syncthreads();                    // prior reads done; vmcnt(0) lands prefetch
            *(uint4*)(ksb + ((kwb     ) ^ kwx)) = pk0;
            *(uint4*)(ksb + ((kwb + 16) ^ kwx)) = pk1;
            *(uint4*)(ksb + ((kwb + 32) ^ kwx)) = pk2;
            *(uint4*)(ksb + ((kwb + 48) ^ kwx)) = pk3;
            *(uint4*)(vsb + ((vwb     ) ^ vwx)) = pv0;
            *(uint4*)(vsb + ((vwb + 16) ^ vwx)) = pv1;
            *(uint4*)(vsb + ((vwb + 32) ^ vwx)) = pv2;
            *(uint4*)(vsb + ((vwb + 48) ^ vwx)) = pv3;
            __syncthreads();                    // LDS tile visible to all waves

            if (!diag) {                        // next tile exists (kv0+64 <= qb)
                const unsigned short* ks = kbase + (size_t)(kv0 + 64) * NDK;
                pk0 = *(const uint4*)(ks);
                pk1 = *(const uint4*)(ks + 8);
                pk2 = *(const uint4*)(ks + 16);
                pk3 = *(const uint4*)(ks + 24);
                const unsigned short* vs = vbase + kv0 + 64;
                pv0 = *(const uint4*)(vs);
                pv1 = *(const uint4*)(vs + 8);
                pv2 = *(const uint4*)(vs + 16);
                pv3 = *(const uint4*)(vs + 24);
                __builtin_amdgcn_sched_barrier(0);  // pin issue point before compute
            }

            // ---- QK^T: 16 MFMAs ----
            f32x4 sv[4];
            __builtin_amdgcn_s_setprio(1);
            #pragma unroll
            for (int cf = 0; cf < 4; cf++) {
                const int krb = (cf * 16 + l16) * 256 + g * 16;
                f32x4 a = {};
                #pragma unroll
                for (int ks2 = 0; ks2 < 4; ks2++) {
                    bf16x8 kf = *(const bf16x8*)(ksb + ((krb + 64 * ks2) ^ rdx));
                    a = __builtin_amdgcn_mfma_f32_16x16x32_bf16(aq[ks2], kf, a, 0, 0, 0);
                }
                sv[cf] = a;
            }
            __builtin_amdgcn_s_setprio(0);

            // ---- online softmax (exp2 domain, pre-scaled scores, deferred l-sum) ----
            const int kvl = kv0 + l16;
            const int rowb = qb + w * 16 + g * 4;
            #pragma unroll
            for (int i = 0; i < 4; i++) {
                float s0 = sv[0][i];
                float s1 = sv[1][i];
                float s2 = sv[2][i];
                float s3 = sv[3][i];
                if (diag) {
                    int row = rowb + i;
                    if (kvl      > row) s0 = -1e30f;
                    if (kvl + 16 > row) s1 = -1e30f;
                    if (kvl + 32 > row) s2 = -1e30f;
                    if (kvl + 48 > row) s3 = -1e30f;
                }
                float mx = fmaxf(fmaxf(s0, s1), fmaxf(s2, s3));
                mx = fmaxf(mx, __shfl_xor(mx, 1));
                mx = fmaxf(mx, __shfl_xor(mx, 2));
                mx = fmaxf(mx, __shfl_xor(mx, 4));
                mx = fmaxf(mx, __shfl_xor(mx, 8));
                float mnew = fmaxf(m_r[i], mx);
                float fac = exp2f(m_r[i] - mnew);
                float p0 = exp2f(s0 - mnew);
                float p1 = exp2f(s1 - mnew);
                float p2 = exp2f(s2 - mnew);
                float p3 = exp2f(s3 - mnew);
                lv[i] = lv[i] * fac + ((p0 + p1) + (p2 + p3));
                m_r[i] = mnew;
                #pragma unroll
                for (int c8 = 0; c8 < 8; c8++) o[c8][i] *= fac;
                const int pr = g * 4 + i;
                char* pw = psb + w * 2048 + pr * 128;
                const int px = (pr & 7) << 4;
                const int cb2 = l16 << 1;
                *(unsigned short*)(pw + ((cb2)      ^ px)) = f2bf(p0);
                *(unsigned short*)(pw + ((cb2 + 32) ^ px)) = f2bf(p1);
                *(unsigned short*)(pw + ((cb2 + 64) ^ px)) = f2bf(p2);
                *(unsigned short*)(pw + ((cb2 + 96) ^ px)) = f2bf(p3);
            }
            // wave-local LDS RAW (Ps write -> cross-lane read): drain + pin (rule #18)
            asm volatile("s_waitcnt lgkmcnt(0)" ::: "memory");
            __builtin_amdgcn_sched_barrier(0);

            // ---- PV: 16 MFMAs ----
            bf16x8 pf[2];
            #pragma unroll
            for (int kc = 0; kc < 2; kc++)
                pf[kc] = *(const bf16x8*)(psb + w * 2048 + l16 * 128 + ((kc * 64 + g * 16) ^ rdx));
            __builtin_amdgcn_s_setprio(1);
            #pragma unroll
            for (int c8 = 0; c8 < 8; c8++) {
                const int vrb = (c8 * 16 + l16) * 128 + g * 16;
                #pragma unroll
                for (int kc = 0; kc < 2; kc++) {
                    bf16x8 vf = *(const bf16x8*)(vsb + ((vrb + kc * 64) ^ rdx));
                    o[c8] = __builtin_amdgcn_mfma_f32_16x16x32_bf16(pf[kc], vf, o[c8], 0, 0, 0);
                }
            }
            __builtin_amdgcn_s_setprio(0);
        };

        for (int kv0 = 0; kv0 < qb; kv0 += 64) TILE(kv0, false);
        TILE(qb, true);

        #pragma unroll
        for (int i = 0; i < 4; i++) {
            float ls = lv[i];
            ls += __shfl_xor(ls, 1);
            ls += __shfl_xor(ls, 2);
            ls += __shfl_xor(ls, 4);
            ls += __shfl_xor(ls, 8);
            float inv = 1.0f / ls;
            int qrow = qb + w * 16 + g * 4 + i;
            size_t rb = ((size_t)(b * NL + qrow)) * ND + h * NDK;
            #pragma unroll
            for (int c8 = 0; c8 < 8; c8++)
                attn_out[rb + c8 * 16 + l16] = f2bf(o[c8][i] * inv);
        }
    }
}

__global__ void ws_signature_kernel(float* y) { if (threadIdx.x == 0) y[0] = 12345.0f; }

extern "C" void kernel_launch(void* const* d_in, const int* in_sizes, int n_in,
                              void* d_out, int out_size, void* d_ws, size_t ws_size,
                              hipStream_t stream)
{
    const float* x     = (const float*)d_in[0];
    const float* w_qkv = (const float*)d_in[1];
    const float* w_o   = (const float*)d_in[2];
    const float* ct    = (const float*)d_in[3];
    const float* st    = (const float*)d_in[4];

    const size_t NTOK = (size_t)NB * NL * ND;
    float* y_out = (float*)d_out;
    float* k_out = y_out + NTOK;
    float* v_out = y_out + 2 * NTOK;

    const size_t need = (6 * NTOK + 4 * (size_t)ND * ND) * sizeof(unsigned short);
    if (ws_size < need) {
        ws_signature_kernel<<<1, 64, 0, stream>>>(y_out);
        return;
    }
    unsigned short* x_bf  = (unsigned short*)d_ws;
    unsigned short* Wt    = x_bf + NTOK;
    unsigned short* Wt_o  = Wt + (size_t)3 * ND * ND;
    unsigned short* q_raw = Wt_o + (size_t)ND * ND;
    unsigned short* q_bf  = q_raw + NTOK;        // unused (kept for layout)
    unsigned short* k_bf  = q_bf + NTOK;
    unsigned short* Vt    = k_bf + NTOK;
    unsigned short* a_bf  = Vt + NTOK;

    prep_kernel<<<8192, 256, 0, stream>>>(x, x_bf, w_qkv, Wt, w_o, Wt_o);
    gemm_bf16<0><<<1536, 256, 0, stream>>>(x_bf, Wt, nullptr, q_raw, k_out, v_out, ND, 48);
    mid_kernel<<<6144, 256, 0, stream>>>(k_out, k_bf, ct, st, v_out, Vt);
    attn_kernel<<<dim3(32, 16), 256, 0, stream>>>(q_raw, k_bf, Vt, a_bf, ct, st);
    gemm_bf16<1><<<512, 256, 0, stream>>>(a_bf, Wt_o, y_out, nullptr, nullptr, nullptr, ND, 16);
}

// Round 9
// 316.050 us; speedup vs baseline: 1.1452x; 1.1452x over previous
//
#include <hip/hip_runtime.h>
#include <hip/hip_bf16.h>

#define NB 2
#define NL 2048
#define ND 2048
#define NH 16
#define NDK 128
// SCALE * log2(e): softmax tracked in exp2 domain; folded into Q at RoPE-convert time
#define SCALE2 0.12753102866606474f

#define AS1 __attribute__((address_space(1)))
#define AS3 __attribute__((address_space(3)))

typedef __attribute__((ext_vector_type(8))) __bf16 bf16x8;
typedef __attribute__((ext_vector_type(4))) float f32x4;

__device__ __forceinline__ unsigned short f2bf(float f) {
    union { float f; unsigned u; } v; v.f = f;
    return (unsigned short)((v.u + 0x7fffu + ((v.u >> 16) & 1u)) >> 16);
}
__device__ __forceinline__ float bf2f(unsigned short h) {
    union { unsigned u; float f; } v; v.u = ((unsigned)h) << 16;
    return v.f;
}

// ============ merged prep: x->bf16 convert + w_qkv transpose + w_o transpose ============
__device__ __forceinline__ void transpose_tile(const float* __restrict__ in,
                                               unsigned short* __restrict__ outp,
                                               int R, int C, int bx, int by, int tid)
{
    __shared__ float T[64][65];
    const int tr0 = by * 64;
    const int tc0 = bx * 64;
    const int r = tid >> 2;
    const int q = tid & 3;
    const float* src = in + (size_t)(tr0 + r) * C + tc0 + q * 16;
    #pragma unroll
    for (int i = 0; i < 4; i++) {
        float4 f = *(const float4*)(src + 4 * i);
        T[r][q * 16 + 4 * i + 0] = f.x;
        T[r][q * 16 + 4 * i + 1] = f.y;
        T[r][q * 16 + 4 * i + 2] = f.z;
        T[r][q * 16 + 4 * i + 3] = f.w;
    }
    __syncthreads();
    unsigned short tmp[16];
    #pragma unroll
    for (int i = 0; i < 16; i++) tmp[i] = f2bf(T[q * 16 + i][r]);
    unsigned short* dst = outp + (size_t)(tc0 + r) * R + tr0 + q * 16;
    *(uint4*)dst       = *(uint4*)&tmp[0];
    *(uint4*)(dst + 8) = *(uint4*)&tmp[8];
}

__global__ __launch_bounds__(256)
void prep_kernel(const float* __restrict__ x, unsigned short* __restrict__ x_bf,
                 const float* __restrict__ w_qkv, unsigned short* __restrict__ Wt,
                 const float* __restrict__ w_o, unsigned short* __restrict__ Wt_o)
{
    const int bid = blockIdx.x;
    const int tid = threadIdx.x;
    if (bid < 4096) {
        int i = bid * 256 + tid;
        const float4 a = ((const float4*)x)[2 * i];
        const float4 b = ((const float4*)x)[2 * i + 1];
        unsigned short t[8] = { f2bf(a.x), f2bf(a.y), f2bf(a.z), f2bf(a.w),
                                f2bf(b.x), f2bf(b.y), f2bf(b.z), f2bf(b.w) };
        ((uint4*)x_bf)[i] = *(uint4*)t;
    } else if (bid < 7168) {
        int b2 = bid - 4096;                      // (96, 32)
        transpose_tile(w_qkv, Wt, ND, 3 * ND, b2 % 96, b2 / 96, tid);
    } else {
        int b3 = bid - 7168;                      // (32, 32)
        transpose_tile(w_o, Wt_o, ND, ND, b3 & 31, b3 >> 5, tid);
    }
}

// ============ pipelined bf16 GEMM (validated): C = A @ Bt^T =============================
// Two barriers per K-step, 3-buffer, vmcnt(8/4/0). DO NOT touch the K-loop schedule:
// rounds 1/2 (4-phase) and 6 (single-barrier) both regressed it (m131-m140 class null).
template<int EPI>
__global__ __launch_bounds__(256)
void gemm_bf16(const unsigned short* __restrict__ A, const unsigned short* __restrict__ Bt,
               float* __restrict__ y_dst,
               unsigned short* __restrict__ q_raw,
               float* __restrict__ k_dst, float* __restrict__ v_dst,
               int K, int NT)
{
    __shared__ __align__(16) unsigned short As[3][128][32];
    __shared__ __align__(16) unsigned short Bs[3][128][32];

    const int tid = threadIdx.x;
    const int lane = tid & 63;
    const int l16 = lane & 15, g = lane >> 4;
    const int w = tid >> 6;
    const int wr = w >> 1, wc = w & 1;

    const int cpn = NT >> 3;
    const int bid = blockIdx.x;
    const int xcd = bid & 7, local = bid >> 3;
    const int bx = xcd * cpn + local % cpn;
    const int by = local / cpn;
    const int m0 = by * 128, n0 = bx * 128;

    const int rowl = (w << 4) + (lane >> 2);
    const int swl = (rowl >> 1) & 3;
    const int kofl = ((lane & 3) ^ swl) << 3;
    const unsigned short* gA = A + (size_t)(m0 + rowl) * K + kofl;
    const unsigned short* gB = Bt + (size_t)(n0 + rowl) * K + kofl;
    const int ldsoff = (w << 10) + (lane << 4);

    f32x4 acc[4][4] = {};
    const int NTILES = K >> 5;

    auto STAGE = [&](int t, int buf) {
        const int k0 = t << 5;
        char* baseA = (char*)&As[buf][0][0] + ldsoff;
        char* baseB = (char*)&Bs[buf][0][0] + ldsoff;
        #pragma unroll
        for (int i = 0; i < 2; i++) {
            __builtin_amdgcn_global_load_lds((const AS1 void*)(gA + (size_t)i * 64 * K + k0),
                                             (AS3 void*)(baseA + i * 4096), 16, 0, 0);
            __builtin_amdgcn_global_load_lds((const AS1 void*)(gB + (size_t)i * 64 * K + k0),
                                             (AS3 void*)(baseB + i * 4096), 16, 0, 0);
        }
    };

    const int rsw = (l16 >> 1) & 3;

    STAGE(0, 0); STAGE(1, 1);

    int bufC = 0;
    for (int t = 0; t < NTILES; t++) {
        const int bufS = (bufC == 0) ? 2 : bufC - 1;
        if (t + 2 < NTILES) STAGE(t + 2, bufS);
        if (t + 2 < NTILES)      asm volatile("s_waitcnt vmcnt(8)" ::: "memory");
        else if (t + 1 < NTILES) asm volatile("s_waitcnt vmcnt(4)" ::: "memory");
        else                     asm volatile("s_waitcnt vmcnt(0)" ::: "memory");
        __builtin_amdgcn_s_barrier();
        __builtin_amdgcn_sched_barrier(0);

        const char* pa = (const char*)&As[bufC][0][0];
        const char* pb = (const char*)&Bs[bufC][0][0];
        bf16x8 af[4], bfr[4];
        #pragma unroll
        for (int r = 0; r < 4; r++) {
            int row = wr * 64 + r * 16 + l16;
            af[r] = *(const bf16x8*)(pa + row * 64 + ((g ^ rsw) << 4));
        }
        #pragma unroll
        for (int c = 0; c < 4; c++) {
            int row = wc * 64 + c * 16 + l16;
            bfr[c] = *(const bf16x8*)(pb + row * 64 + ((g ^ rsw) << 4));
        }
        #pragma unroll
        for (int r = 0; r < 4; r++)
            #pragma unroll
            for (int c = 0; c < 4; c++)
                acc[r][c] = __builtin_amdgcn_mfma_f32_16x16x32_bf16(af[r], bfr[c], acc[r][c], 0, 0, 0);

        __builtin_amdgcn_s_barrier();
        __builtin_amdgcn_sched_barrier(0);
        bufC = (bufC == 2) ? 0 : bufC + 1;
    }

    if constexpr (EPI == 0) {
        const int m3 = bx >> 4, h = bx & 15;
        #pragma unroll
        for (int r = 0; r < 4; r++) {
            int mrow = m0 + wr * 64 + r * 16 + g * 4;
            int b = mrow >> 11, l = mrow & 2047;
            size_t rb = ((size_t)(b * NH + h) * NL + l) * NDK;
            #pragma unroll
            for (int c = 0; c < 4; c++) {
                int dk = wc * 64 + c * 16 + l16;
                #pragma unroll
                for (int i = 0; i < 4; i++) {
                    float val = acc[r][c][i];
                    size_t off = rb + (size_t)i * NDK + dk;
                    if (m3 == 0) q_raw[off] = f2bf(val);
                    else if (m3 == 1) k_dst[off] = val;
                    else v_dst[off] = val;
                }
            }
        }
    } else {
        #pragma unroll
        for (int r = 0; r < 4; r++) {
            int mrow = m0 + wr * 64 + r * 16 + g * 4;
            #pragma unroll
            for (int c = 0; c < 4; c++) {
                int ncol = n0 + wc * 64 + c * 16 + l16;
                #pragma unroll
                for (int i = 0; i < 4; i++)
                    y_dst[(size_t)(mrow + i) * ND + ncol] = acc[r][c][i];
            }
        }
    }
}

// ============ merged mid: RoPE-k (float4) + per-head V transpose ========================
__global__ __launch_bounds__(256)
void mid_kernel(float* __restrict__ kp, unsigned short* __restrict__ k_bf,
                const float* __restrict__ ct, const float* __restrict__ st,
                const float* __restrict__ v, unsigned short* __restrict__ vt)
{
    const int bid = blockIdx.x;
    const int tid = threadIdx.x;
    if (bid < 4096) {
        int idx = bid * 256 + tid;
        int d = (idx & 15) << 2;
        int rr = idx >> 4;
        size_t ro = (size_t)rr * NDK;
        int l = rr & (NL - 1);
        float4 c  = *(const float4*)(ct + l * 64 + d);
        float4 s  = *(const float4*)(st + l * 64 + d);
        float4 t1 = *(const float4*)(kp + ro + d);
        float4 t2 = *(const float4*)(kp + ro + d + 64);
        float4 o1, o2;
        o1.x = t1.x * c.x - t2.x * s.x;  o2.x = t1.x * s.x + t2.x * c.x;
        o1.y = t1.y * c.y - t2.y * s.y;  o2.y = t1.y * s.y + t2.y * c.y;
        o1.z = t1.z * c.z - t2.z * s.z;  o2.z = t1.z * s.z + t2.z * c.z;
        o1.w = t1.w * c.w - t2.w * s.w;  o2.w = t1.w * s.w + t2.w * c.w;
        *(float4*)(kp + ro + d)      = o1;
        *(float4*)(kp + ro + d + 64) = o2;
        unsigned short u1[4] = { f2bf(o1.x), f2bf(o1.y), f2bf(o1.z), f2bf(o1.w) };
        unsigned short u2[4] = { f2bf(o2.x), f2bf(o2.y), f2bf(o2.z), f2bf(o2.w) };
        *(uint2*)(k_bf + ro + d)      = *(uint2*)u1;
        *(uint2*)(k_bf + ro + d + 64) = *(uint2*)u2;
    } else {
        __shared__ float T[64][65];
        int b2 = bid - 4096;                  // (2, 32, 32)
        const int bh = b2 >> 6;
        const int l0 = ((b2 >> 1) & 31) * 64;
        const int d0 = (b2 & 1) * 64;
        const int r = tid >> 2;
        const int q = tid & 3;
        const float* src = v + (size_t)bh * NL * NDK + (size_t)(l0 + r) * NDK + d0 + q * 16;
        #pragma unroll
        for (int i = 0; i < 4; i++) {
            float4 f = *(const float4*)(src + 4 * i);
            T[r][q * 16 + 4 * i + 0] = f.x;
            T[r][q * 16 + 4 * i + 1] = f.y;
            T[r][q * 16 + 4 * i + 2] = f.z;
            T[r][q * 16 + 4 * i + 3] = f.w;
        }
        __syncthreads();
        unsigned short tmp[16];
        #pragma unroll
        for (int i = 0; i < 16; i++) tmp[i] = f2bf(T[q * 16 + i][r]);
        unsigned short* dst = vt + (size_t)bh * NDK * NL + (size_t)(d0 + r) * NL + l0 + q * 16;
        *(uint4*)dst       = *(uint4*)&tmp[0];
        *(uint4*)(dst + 8) = *(uint4*)&tmp[8];
    }
}

// ============ MFMA flash attention (round-7 validated inline structure) =================
// grid (32 bh, 16 by); block does jq = 31-by then by -> perfect balance (33 units/block)
// + L2-warm K/V reuse. T14 prefetch into NAMED uint4 registers, INLINE loop body only --
// NO lambda around the tile (round-8/round-11 post-mortem: lambda-captured mutable uint4
// state spills to scratch, VGPR 152->132, 2x slowdown). Mask applied every tile (cheap,
// proven). Only round-9 delta vs round-7: SCALE2 folded into Q's cos/sin at RoPE time
// (verified absmax-identical in round 8).
__global__ __launch_bounds__(256)
void attn_kernel(const unsigned short* __restrict__ q,
                 const unsigned short* __restrict__ k,
                 const unsigned short* __restrict__ vt,
                 unsigned short* __restrict__ attn_out,
                 const float* __restrict__ ct, const float* __restrict__ st)
{
    __shared__ __align__(16) unsigned short Ks[64][128];
    __shared__ __align__(16) unsigned short Vts[128][64];
    __shared__ __align__(16) unsigned short Ps[4][16][64];

    char* const ksb = (char*)&Ks[0][0];
    char* const vsb = (char*)&Vts[0][0];
    char* const psb = (char*)&Ps[0][0][0];

    const int tid = threadIdx.x, lane = tid & 63, w = tid >> 6;
    const int l16 = lane & 15, g = lane >> 4;
    const int bh = blockIdx.x;
    const int b = bh >> 4, h = bh & 15;
    const size_t base = (size_t)bh * NL * NDK;

    const int krow = tid >> 2;
    const int kq = tid & 3;
    const int kwb = krow * 256 + kq * 64;
    const int kwx = (krow & 7) << 4;
    const int vrow = tid >> 1;
    const int vh = tid & 1;
    const int vwb = vrow * 128 + vh * 64;
    const int vwx = (vrow & 7) << 4;

    const int rdx = (l16 & 7) << 4;

    const unsigned short* const kbase = k + base + (size_t)krow * NDK + kq * 32;
    const unsigned short* const vbase = vt + base + (size_t)vrow * NL + vh * 32;

    for (int half = 0; half < 2; half++) {
        const int jq = half ? (int)blockIdx.y : 31 - (int)blockIdx.y;
        const int qb = jq * 64;

        // ---- Q load with fused RoPE (SCALE2 folded into cos/sin) ----
        bf16x8 aq[4];
        {
            const int l = qb + w * 16 + l16;
            const unsigned short* src = q + base + (size_t)l * NDK + g * 8;
            union { bf16x8 v; unsigned short s[8]; } raw[4], outv[4];
            #pragma unroll
            for (int ks2 = 0; ks2 < 4; ks2++) raw[ks2].v = *(const bf16x8*)(src + ks2 * 32);
            const float* cb = ct + (size_t)l * 64 + g * 8;
            const float* sb = st + (size_t)l * 64 + g * 8;
            float cv[2][8], sv2[2][8];
            #pragma unroll
            for (int hh = 0; hh < 2; hh++) {
                float4 c0 = *(const float4*)(cb + 32 * hh);
                float4 c1 = *(const float4*)(cb + 32 * hh + 4);
                float4 s0 = *(const float4*)(sb + 32 * hh);
                float4 s1 = *(const float4*)(sb + 32 * hh + 4);
                cv[hh][0]=c0.x*SCALE2; cv[hh][1]=c0.y*SCALE2; cv[hh][2]=c0.z*SCALE2; cv[hh][3]=c0.w*SCALE2;
                cv[hh][4]=c1.x*SCALE2; cv[hh][5]=c1.y*SCALE2; cv[hh][6]=c1.z*SCALE2; cv[hh][7]=c1.w*SCALE2;
                sv2[hh][0]=s0.x*SCALE2; sv2[hh][1]=s0.y*SCALE2; sv2[hh][2]=s0.z*SCALE2; sv2[hh][3]=s0.w*SCALE2;
                sv2[hh][4]=s1.x*SCALE2; sv2[hh][5]=s1.y*SCALE2; sv2[hh][6]=s1.z*SCALE2; sv2[hh][7]=s1.w*SCALE2;
            }
            #pragma unroll
            for (int hh = 0; hh < 2; hh++)
                #pragma unroll
                for (int j = 0; j < 8; j++) {
                    float t1 = bf2f(raw[hh].s[j]), t2 = bf2f(raw[hh + 2].s[j]);
                    float c = cv[hh][j], s = sv2[hh][j];
                    outv[hh].s[j]     = f2bf(t1 * c - t2 * s);
                    outv[hh + 2].s[j] = f2bf(t1 * s + t2 * c);
                }
            #pragma unroll
            for (int ks2 = 0; ks2 < 4; ks2++) aq[ks2] = outv[ks2].v;
        }

        f32x4 o[8] = {};
        float m_r[4], lv[4];
        #pragma unroll
        for (int i = 0; i < 4; i++) { m_r[i] = -1e30f; lv[i] = 0.f; }

        // ---- T14 prologue: tile 0 into named registers ----
        uint4 pk0, pk1, pk2, pk3, pv0, pv1, pv2, pv3;
        {
            const unsigned short* ks = kbase;           // kv0 = 0
            pk0 = *(const uint4*)(ks);
            pk1 = *(const uint4*)(ks + 8);
            pk2 = *(const uint4*)(ks + 16);
            pk3 = *(const uint4*)(ks + 24);
            const unsigned short* vs = vbase;
            pv0 = *(const uint4*)(vs);
            pv1 = *(const uint4*)(vs + 8);
            pv2 = *(const uint4*)(vs + 16);
            pv3 = *(const uint4*)(vs + 24);
        }

        for (int kv0 = 0; kv0 <= qb; kv0 += 64) {
            __syncthreads();                    // prior reads done; vmcnt(0) lands prefetch
            *(uint4*)(ksb + ((kwb     ) ^ kwx)) = pk0;
            *(uint4*)(ksb + ((kwb + 16) ^ kwx)) = pk1;
            *(uint4*)(ksb + ((kwb + 32) ^ kwx)) = pk2;
            *(uint4*)(ksb + ((kwb + 48) ^ kwx)) = pk3;
            *(uint4*)(vsb + ((vwb     ) ^ vwx)) = pv0;
            *(uint4*)(vsb + ((vwb + 16) ^ vwx)) = pv1;
            *(uint4*)(vsb + ((vwb + 32) ^ vwx)) = pv2;
            *(uint4*)(vsb + ((vwb + 48) ^ vwx)) = pv3;
            __syncthreads();                    // LDS tile visible to all waves

            if (kv0 + 64 <= qb) {               // T14: issue next tile now (inline, named)
                const unsigned short* ks = kbase + (size_t)(kv0 + 64) * NDK;
                pk0 = *(const uint4*)(ks);
                pk1 = *(const uint4*)(ks + 8);
                pk2 = *(const uint4*)(ks + 16);
                pk3 = *(const uint4*)(ks + 24);
                const unsigned short* vs = vbase + kv0 + 64;
                pv0 = *(const uint4*)(vs);
                pv1 = *(const uint4*)(vs + 8);
                pv2 = *(const uint4*)(vs + 16);
                pv3 = *(const uint4*)(vs + 24);
                __builtin_amdgcn_sched_barrier(0);  // pin issue point before compute
            }

            // ---- QK^T: 16 MFMAs ----
            f32x4 sv[4];
            __builtin_amdgcn_s_setprio(1);
            #pragma unroll
            for (int cf = 0; cf < 4; cf++) {
                const int krb = (cf * 16 + l16) * 256 + g * 16;
                f32x4 a = {};
                #pragma unroll
                for (int ks2 = 0; ks2 < 4; ks2++) {
                    bf16x8 kf = *(const bf16x8*)(ksb + ((krb + 64 * ks2) ^ rdx));
                    a = __builtin_amdgcn_mfma_f32_16x16x32_bf16(aq[ks2], kf, a, 0, 0, 0);
                }
                sv[cf] = a;
            }
            __builtin_amdgcn_s_setprio(0);

            // ---- online softmax (exp2 domain, pre-scaled scores, deferred l-sum) ----
            const int kvl = kv0 + l16;
            const int rowb = qb + w * 16 + g * 4;
            #pragma unroll
            for (int i = 0; i < 4; i++) {
                int row = rowb + i;
                float s0 = sv[0][i];
                float s1 = sv[1][i];
                float s2 = sv[2][i];
                float s3 = sv[3][i];
                if (kvl      > row) s0 = -1e30f;
                if (kvl + 16 > row) s1 = -1e30f;
                if (kvl + 32 > row) s2 = -1e30f;
                if (kvl + 48 > row) s3 = -1e30f;
                float mx = fmaxf(fmaxf(s0, s1), fmaxf(s2, s3));
                mx = fmaxf(mx, __shfl_xor(mx, 1));
                mx = fmaxf(mx, __shfl_xor(mx, 2));
                mx = fmaxf(mx, __shfl_xor(mx, 4));
                mx = fmaxf(mx, __shfl_xor(mx, 8));
                float mnew = fmaxf(m_r[i], mx);
                float fac = exp2f(m_r[i] - mnew);
                float p0 = exp2f(s0 - mnew);
                float p1 = exp2f(s1 - mnew);
                float p2 = exp2f(s2 - mnew);
                float p3 = exp2f(s3 - mnew);
                lv[i] = lv[i] * fac + ((p0 + p1) + (p2 + p3));
                m_r[i] = mnew;
                #pragma unroll
                for (int c8 = 0; c8 < 8; c8++) o[c8][i] *= fac;
                const int pr = g * 4 + i;
                char* pw = psb + w * 2048 + pr * 128;
                const int px = (pr & 7) << 4;
                const int cb2 = l16 << 1;
                *(unsigned short*)(pw + ((cb2)      ^ px)) = f2bf(p0);
                *(unsigned short*)(pw + ((cb2 + 32) ^ px)) = f2bf(p1);
                *(unsigned short*)(pw + ((cb2 + 64) ^ px)) = f2bf(p2);
                *(unsigned short*)(pw + ((cb2 + 96) ^ px)) = f2bf(p3);
            }
            // wave-local LDS RAW (Ps write -> cross-lane read): drain + pin (rule #18)
            asm volatile("s_waitcnt lgkmcnt(0)" ::: "memory");
            __builtin_amdgcn_sched_barrier(0);

            // ---- PV: 16 MFMAs ----
            bf16x8 pf[2];
            #pragma unroll
            for (int kc = 0; kc < 2; kc++)
                pf[kc] = *(const bf16x8*)(psb + w * 2048 + l16 * 128 + ((kc * 64 + g * 16) ^ rdx));
            __builtin_amdgcn_s_setprio(1);
            #pragma unroll
            for (int c8 = 0; c8 < 8; c8++) {
                const int vrb = (c8 * 16 + l16) * 128 + g * 16;
                #pragma unroll
                for (int kc = 0; kc < 2; kc++) {
                    bf16x8 vf = *(const bf16x8*)(vsb + ((vrb + kc * 64) ^ rdx));
                    o[c8] = __builtin_amdgcn_mfma_f32_16x16x32_bf16(pf[kc], vf, o[c8], 0, 0, 0);
                }
            }
            __builtin_amdgcn_s_setprio(0);
        }

        #pragma unroll
        for (int i = 0; i < 4; i++) {
            float ls = lv[i];
            ls += __shfl_xor(ls, 1);
            ls += __shfl_xor(ls, 2);
            ls += __shfl_xor(ls, 4);
            ls += __shfl_xor(ls, 8);
            float inv = 1.0f / ls;
            int qrow = qb + w * 16 + g * 4 + i;
            size_t rb = ((size_t)(b * NL + qrow)) * ND + h * NDK;
            #pragma unroll
            for (int c8 = 0; c8 < 8; c8++)
                attn_out[rb + c8 * 16 + l16] = f2bf(o[c8][i] * inv);
        }
    }
}

__global__ void ws_signature_kernel(float* y) { if (threadIdx.x == 0) y[0] = 12345.0f; }

extern "C" void kernel_launch(void* const* d_in, const int* in_sizes, int n_in,
                              void* d_out, int out_size, void* d_ws, size_t ws_size,
                              hipStream_t stream)
{
    const float* x     = (const float*)d_in[0];
    const float* w_qkv = (const float*)d_in[1];
    const float* w_o   = (const float*)d_in[2];
    const float* ct    = (const float*)d_in[3];
    const float* st    = (const float*)d_in[4];

    const size_t NTOK = (size_t)NB * NL * ND;
    float* y_out = (float*)d_out;
    float* k_out = y_out + NTOK;
    float* v_out = y_out + 2 * NTOK;

    const size_t need = (6 * NTOK + 4 * (size_t)ND * ND) * sizeof(unsigned short);
    if (ws_size < need) {
        ws_signature_kernel<<<1, 64, 0, stream>>>(y_out);
        return;
    }
    unsigned short* x_bf  = (unsigned short*)d_ws;
    unsigned short* Wt    = x_bf + NTOK;
    unsigned short* Wt_o  = Wt + (size_t)3 * ND * ND;
    unsigned short* q_raw = Wt_o + (size_t)ND * ND;
    unsigned short* q_bf  = q_raw + NTOK;        // unused (kept for layout)
    unsigned short* k_bf  = q_bf + NTOK;
    unsigned short* Vt    = k_bf + NTOK;
    unsigned short* a_bf  = Vt + NTOK;

    prep_kernel<<<8192, 256, 0, stream>>>(x, x_bf, w_qkv, Wt, w_o, Wt_o);
    gemm_bf16<0><<<1536, 256, 0, stream>>>(x_bf, Wt, nullptr, q_raw, k_out, v_out, ND, 48);
    mid_kernel<<<6144, 256, 0, stream>>>(k_out, k_bf, ct, st, v_out, Vt);
    attn_kernel<<<dim3(32, 16), 256, 0, stream>>>(q_raw, k_bf, Vt, a_bf, ct, st);
    gemm_bf16<1><<<512, 256, 0, stream>>>(a_bf, Wt_o, y_out, nullptr, nullptr, nullptr, ND, 16);
}